// Round 8
// baseline (299.323 us; speedup 1.0000x reference)
//
#include <hip/hip_runtime.h>
#include <cstdint>
#include <cstddef>

using bf16   = __bf16;
using bf16x8 = __bf16 __attribute__((ext_vector_type(8)));
using f32x4  = float  __attribute__((ext_vector_type(4)));
using u16    = unsigned short;
using ushort8 = __attribute__((ext_vector_type(8))) unsigned short;

#define MFMA16(a, b, c) __builtin_amdgcn_mfma_f32_16x16x32_bf16(a, b, c, 0, 0, 0)

__device__ __forceinline__ u16 f2bf(float f) {
  union { float f; unsigned u; } v; v.f = f;
  unsigned r = v.u + 0x7fffu + ((v.u >> 16) & 1u);
  return (u16)(r >> 16);
}
__device__ __forceinline__ u16 bfc(float f) {
  union { float f; unsigned u; } v; v.f = f;
  return (u16)((v.u + 0x8000u) >> 16);
}
__device__ __forceinline__ float b2f(u16 h) {
  union { unsigned u; float f; } v; v.u = ((unsigned)h) << 16; return v.f;
}
__device__ __forceinline__ bf16x8 ldb8(const u16* p) { return *(const bf16x8*)p; }
__device__ __forceinline__ float red_sum16(float v) {
  v += __shfl_xor(v, 1, 64); v += __shfl_xor(v, 2, 64);
  v += __shfl_xor(v, 4, 64); v += __shfl_xor(v, 8, 64);
  return v;
}
__device__ __forceinline__ void gll16(const u16* g, u16* l) {
  __builtin_amdgcn_global_load_lds(
      (const __attribute__((address_space(1))) void*)g,
      (__attribute__((address_space(3))) void*)l, 16, 0, 0);
}

#define QSCALE 0.09016844005556021f  // C^-0.5 * log2(e)

// ---------- prep: weight converts/transposes ----------
__global__ void k_prep(const float* __restrict__ kv_w2, const float* __restrict__ kv_w3,
                       const float* __restrict__ kv_w4, const float* __restrict__ q_w,
                       const float* __restrict__ proj_w,
                       u16* __restrict__ Wt2, u16* __restrict__ Wt3, u16* __restrict__ Wt4,
                       u16* __restrict__ Qw, u16* __restrict__ Pww) {
  int idx = blockIdx.x * 256 + threadIdx.x;
  if (idx < 32768) {                    // kv_w2 [128][256] -> Wt2 [256][128]
    int n = idx >> 7, k = idx & 127;
    Wt2[idx] = f2bf(kv_w2[k * 256 + n]);
  } else if (idx < 98304) {             // kv_w3 [256][256] -> Wt3 [256][256]
    int j = idx - 32768, n = j >> 8, k = j & 255;
    Wt3[j] = f2bf(kv_w3[k * 256 + n]);
  } else if (idx < 229376) {            // kv_w4 [256][512] -> Wt4 [512][256]
    int j = idx - 98304, n = j >> 8, k = j & 255;
    Wt4[j] = f2bf(kv_w4[k * 512 + n]);
  } else if (idx < 294912) {            // q_w already [o][c]
    int j = idx - 229376;
    Qw[j] = f2bf(q_w[j]);
  } else if (idx < 360448) {
    int j = idx - 294912;
    Pww[j] = f2bf(proj_w[j]);
  }
}

// ---------- wave-local MLP layer: B-frags direct from L2, zero barriers ----------
// act: per-wave [16][264]. LN + leaky fused; writes act back (C->A bounce), wave-local wait.
template<int K>
__device__ __forceinline__ void wave_layer(u16* act, const u16* __restrict__ Wt,
    const float* __restrict__ bias, const float* __restrict__ g, const float* __restrict__ bb,
    int quad, int l16) {
  bf16x8 af[K / 32];
  #pragma unroll
  for (int kk = 0; kk < K / 32; ++kk) af[kk] = ldb8(act + l16 * 264 + kk * 32 + quad * 8);
  f32x4 z = {0.f, 0.f, 0.f, 0.f};
  f32x4 acc[16];
  #pragma unroll
  for (int f = 0; f < 16; ++f) acc[f] = z;
  #pragma unroll
  for (int nb = 0; nb < 16; ++nb) {
    const u16* wrow = Wt + (size_t)(nb * 16 + l16) * K + quad * 8;
    #pragma unroll
    for (int kk = 0; kk < K / 32; ++kk)
      acc[nb] = MFMA16(af[kk], ldb8(wrow + kk * 32), acc[nb]);
  }
  #pragma unroll
  for (int f = 0; f < 16; ++f) {
    float bv = bias[f * 16 + l16];
    acc[f][0] += bv; acc[f][1] += bv; acc[f][2] += bv; acc[f][3] += bv;
  }
  #pragma unroll
  for (int r = 0; r < 4; ++r) {
    float s = 0;
    #pragma unroll
    for (int f = 0; f < 16; ++f) s += acc[f][r];
    s = red_sum16(s);
    float mu = s * (1.f / 256.f);
    float vv = 0;
    #pragma unroll
    for (int f = 0; f < 16; ++f) { float d = acc[f][r] - mu; vv += d * d; }
    vv = red_sum16(vv);
    float inv = rsqrtf(vv * (1.f / 256.f) + 1e-5f);
    int rl = quad * 4 + r;
    #pragma unroll
    for (int f = 0; f < 16; ++f) {
      int col = f * 16 + l16;
      float o = (acc[f][r] - mu) * inv * g[col] + bb[col];
      o = o > 0.f ? o : 0.01f * o;
      act[rl * 264 + col] = f2bf(o);
    }
  }
  asm volatile("s_waitcnt lgkmcnt(0)" ::: "memory");  // act writes visible to this wave's reads
}

// ---------- fused: [blocks 0..255] wave-independent KV-MLP; [256..511] Q-GEMM ----------
__global__ __launch_bounds__(256, 2) void k_fused(
    const float* __restrict__ x, const float* __restrict__ w1, const float* __restrict__ bias1,
    const float* __restrict__ g1, const float* __restrict__ bb1,
    const u16* __restrict__ Wt2, const float* __restrict__ bias2,
    const float* __restrict__ g2, const float* __restrict__ bb2,
    const u16* __restrict__ Wt3, const float* __restrict__ bias3,
    const float* __restrict__ g3, const float* __restrict__ bb3,
    const u16* __restrict__ Wt4, const float* __restrict__ bias4,
    const float* __restrict__ y, const u16* __restrict__ Qw,
    const float* __restrict__ qb, const float* __restrict__ dww, const float* __restrict__ dwb,
    u16* __restrict__ Kt, u16* __restrict__ Vt, u16* __restrict__ Qb) {
  __shared__ __align__(16) u16 smem[23040];   // MLP: 4 x [16][264] act; Q: sY+sB
  int tid = threadIdx.x, w = tid >> 6, lane = tid & 63, quad = lane >> 4, l16 = lane & 15;

  if (blockIdx.x < 256) {
    // ===== KV-MLP: each wave owns 16 rows end-to-end; no block barriers =====
    u16* act = smem + w * 4224;     // per-wave [16][264]
    int i0b = blockIdx.x * 64;
    int rbase = i0b + w * 16;
    {   // layer 1: thread (quad,l16): row l16, cols quad*32..+32
      int c0 = quad * 32;
      float xv = x[rbase + l16];
      float t[32];
      float s = 0.f;
      #pragma unroll
      for (int j = 0; j < 32; ++j) { t[j] = xv * w1[c0 + j] + bias1[c0 + j]; s += t[j]; }
      s += __shfl_xor(s, 16, 64); s += __shfl_xor(s, 32, 64);
      float mu = s * (1.f / 128.f);
      float vv = 0.f;
      #pragma unroll
      for (int j = 0; j < 32; ++j) { float d = t[j] - mu; vv += d * d; }
      vv += __shfl_xor(vv, 16, 64); vv += __shfl_xor(vv, 32, 64);
      float inv = rsqrtf(vv * (1.f / 128.f) + 1e-5f);
      #pragma unroll
      for (int jo = 0; jo < 4; ++jo) {
        ushort8 pk;
        #pragma unroll
        for (int e = 0; e < 8; ++e) {
          int j = jo * 8 + e;
          float o = (t[j] - mu) * inv * g1[c0 + j] + bb1[c0 + j];
          o = o > 0.f ? o : 0.01f * o;
          pk[e] = f2bf(o);
        }
        *(ushort8*)(act + l16 * 264 + c0 + jo * 8) = pk;
      }
    }
    asm volatile("s_waitcnt lgkmcnt(0)" ::: "memory");
    wave_layer<128>(act, Wt2, bias2, g2, bb2, quad, l16);
    wave_layer<256>(act, Wt3, bias3, g3, bb3, quad, l16);
    // ---- layer 4: two N-halves, silu, K/V swizzled tile stores ----
    {
      bf16x8 af[8];
      #pragma unroll
      for (int kk = 0; kk < 8; ++kk) af[kk] = ldb8(act + l16 * 264 + kk * 32 + quad * 8);
      f32x4 z = {0.f, 0.f, 0.f, 0.f};
      for (int h = 0; h < 2; ++h) {
        f32x4 acc[16];
        #pragma unroll
        for (int f = 0; f < 16; ++f) acc[f] = z;
        #pragma unroll
        for (int nb = 0; nb < 16; ++nb) {
          const u16* wrow = Wt4 + (size_t)(h * 256 + nb * 16 + l16) * 256 + quad * 8;
          #pragma unroll
          for (int kk = 0; kk < 8; ++kk)
            acc[nb] = MFMA16(af[kk], ldb8(wrow + kk * 32), acc[nb]);
        }
        #pragma unroll
        for (int f = 0; f < 16; ++f) {
          int col = f * 16 + l16;
          float bv = bias4[h * 256 + col];
          if (h == 0) {
            int chunk = f * 2 + (l16 >> 3), co = col & 7;
            #pragma unroll
            for (int r = 0; r < 4; ++r) {
              int rowg = rbase + quad * 4 + r;
              float v = acc[f][r] + bv;
              v = v / (1.f + __expf(-v));
              int chs = (chunk + (rowg & 31)) & 31;
              Kt[(size_t)rowg * 256 + chs * 8 + co] = f2bf(v);
            }
          } else {
            int rowg0 = rbase + quad * 4;
            int bb2_ = rowg0 >> 12, d0 = rowg0 & 4095;
            int dd = d0 & 31, qd = dd >> 3;
            int chs = (qd + (col & 3) + ((col >> 2) & 3)) & 3;
            ushort4 u;
            #pragma unroll
            for (int r = 0; r < 4; ++r) {
              float v = acc[f][r] + bv;
              v = v / (1.f + __expf(-v));
              ((u16*)&u)[r] = f2bf(v);
            }
            size_t off = ((size_t)(bb2_ * 128 + (d0 >> 5)) * 8192) + col * 32 + chs * 8 + (dd & 7);
            *(ushort4*)(Vt + off) = u;
          }
        }
      }
    }
    return;
  }

  // ===== Q-GEMM partition: 64-row tiles, pre-scaled by QSCALE =====
  u16* sY = smem;              // [64][72]
  u16* sB = smem + 4608;       // [256][72]
  int t = blockIdx.x - 256;
  int b = t >> 6, i0 = (t & 63) * 64;
  f32x4 z = {0.f, 0.f, 0.f, 0.f};
  f32x4 acc[16];
  #pragma unroll
  for (int f = 0; f < 16; ++f) acc[f] = z;
  for (int kc = 0; kc < 4; ++kc) {
    if (kc) __syncthreads();
    {   // transpose-stage y[b][c][i] -> sY[i][c] (fp32 -> bf16)
      int cl = tid >> 4;
      int il = (tid & 15) * 4;
      #pragma unroll
      for (int p = 0; p < 4; ++p) {
        int c = kc * 64 + p * 16 + cl;
        float4 v = *(const float4*)(y + ((size_t)(b * 256 + c)) * 4096 + i0 + il);
        sY[(il + 0) * 72 + p * 16 + cl] = f2bf(v.x);
        sY[(il + 1) * 72 + p * 16 + cl] = f2bf(v.y);
        sY[(il + 2) * 72 + p * 16 + cl] = f2bf(v.z);
        sY[(il + 3) * 72 + p * 16 + cl] = f2bf(v.w);
      }
    }
    #pragma unroll
    for (int p = 0; p < 8; ++p) {
      int q = p * 256 + tid; int row = q >> 3, k8 = q & 7;
      *(uint4*)(sB + row * 72 + k8 * 8) = *(const uint4*)(Qw + (size_t)row * 256 + kc * 64 + k8 * 8);
    }
    __syncthreads();
    #pragma unroll
    for (int kk = 0; kk < 2; ++kk) {
      bf16x8 af = ldb8(sY + (w * 16 + l16) * 72 + kk * 32 + quad * 8);
      #pragma unroll
      for (int f = 0; f < 16; ++f) {
        bf16x8 bfr = ldb8(sB + (f * 16 + l16) * 72 + kk * 32 + quad * 8);
        acc[f] = MFMA16(af, bfr, acc[f]);
      }
    }
  }
  #pragma unroll
  for (int f = 0; f < 16; ++f) {
    int col = f * 16 + l16;
    float q0 = qb[col], sc = dww[col], dB = dwb[col];
    #pragma unroll
    for (int r = 0; r < 4; ++r) {
      int rowg = i0 + w * 16 + quad * 4 + r;
      float v = ((acc[f][r] + q0) * sc + dB) * QSCALE;
      Qb[((size_t)(b * 4096 + rowg)) * 256 + col] = f2bf(v);
    }
  }
}

// ---------- flash attention: r6 structure + de-conflicted P bounce ----------
// P rowbase = row*40 + quad*8 (+8 u16 per quad-group): store bank bases per quad
// become {0,20,8,28}+20r -> <=2-way (free, m136); 16B alignment preserved.
__global__ __launch_bounds__(256, 2) void k_attn(const u16* __restrict__ Qb, const u16* __restrict__ Kt,
    const u16* __restrict__ Vt, u16* __restrict__ Op, float* __restrict__ Ol) {
  __shared__ __align__(16) u16 smem[38144];   // [2][16384] K+V dbuf + [4][1344] P
  int tid = threadIdx.x, w = tid >> 6, lane = tid & 63, quad = lane >> 4, l16 = lane & 15;
  int b = blockIdx.x & 3, kh = (blockIdx.x >> 2) & 3, qt = blockIdx.x >> 4;
  int i0 = qt * 128 + w * 32;

  bf16x8 qf[2][8];
  {
    const u16* qrow = Qb + ((size_t)(b * 4096 + i0 + l16)) * 256 + quad * 8;
    #pragma unroll
    for (int kk = 0; kk < 8; ++kk) {
      qf[0][kk] = ldb8(qrow + kk * 32);
      qf[1][kk] = ldb8(qrow + 16 * 256 + kk * 32);
    }
  }
  f32x4 z = {0.f, 0.f, 0.f, 0.f};
  f32x4 oacc[2][16];
  #pragma unroll
  for (int sub = 0; sub < 2; ++sub)
    #pragma unroll
    for (int f = 0; f < 16; ++f) oacc[sub][f] = z;
  float l4[2][4] = {{0.f, 0.f, 0.f, 0.f}, {0.f, 0.f, 0.f, 0.f}};

  u16* sPw = smem + 32768 + w * 1344;
  int wp = w & 1;
  const u16* gSrc = ((w < 2) ? Kt : Vt) + ((size_t)(b * 128 + kh * 32) * 8192) + wp * 4096 + lane * 8;
  u16* lBase = smem + ((w < 2) ? 0 : 8192) + wp * 4096 + lane * 8;

  #pragma unroll
  for (int i = 0; i < 8; ++i) gll16(gSrc + i * 512, lBase + i * 512);
  gSrc += 8192;

  #pragma unroll 1
  for (int kt = 0; kt < 32; ++kt) {
    int buf = kt & 1;
    const u16* sK = smem + buf * 16384;
    const u16* sV = sK + 8192;
    asm volatile("s_waitcnt vmcnt(0)" ::: "memory");
    __syncthreads();
    if (kt < 31) {
      u16* dst = lBase + (buf ^ 1) * 16384;
      #pragma unroll
      for (int i = 0; i < 8; ++i) gll16(gSrc + i * 512, dst + i * 512);
      gSrc += 8192;
    }
    f32x4 s00 = z, s01 = z, s10 = z, s11 = z;
    #pragma unroll
    for (int kk = 0; kk < 8; ++kk) {
      int ch0 = (kk * 4 + quad + l16) & 31;
      int ch1 = (ch0 + 16) & 31;
      bf16x8 k0 = ldb8(sK + l16 * 256 + ch0 * 8);
      bf16x8 k1 = ldb8(sK + (16 + l16) * 256 + ch1 * 8);
      s00 = MFMA16(qf[0][kk], k0, s00);
      s01 = MFMA16(qf[0][kk], k1, s01);
      s10 = MFMA16(qf[1][kk], k0, s10);
      s11 = MFMA16(qf[1][kk], k1, s11);
    }
    #pragma unroll
    for (int r = 0; r < 4; ++r) {
      float p0 = exp2f(s00[r]);
      float p1 = exp2f(s01[r]);
      float p2 = exp2f(s10[r]);
      float p3 = exp2f(s11[r]);
      l4[0][r] += p0 + p1;
      l4[1][r] += p2 + p3;
      int row0 = (quad * 4 + r) * 40 + quad * 8;   // de-conflicted rowbase
      sPw[row0 + l16]             = bfc(p0);
      sPw[row0 + 16 + l16]        = bfc(p1);
      sPw[672 + row0 + l16]       = bfc(p2);
      sPw[672 + row0 + 16 + l16]  = bfc(p3);
    }
    asm volatile("s_waitcnt lgkmcnt(0)" ::: "memory");
    int prow = l16 * 40 + (l16 >> 2) * 8 + quad * 8;
    bf16x8 pf0 = ldb8(sPw + prow);
    bf16x8 pf1 = ldb8(sPw + 672 + prow);
    #pragma unroll
    for (int f = 0; f < 16; ++f) {
      int c = f * 16 + l16;
      int chs = (quad + (c & 3) + ((c >> 2) & 3)) & 3;
      bf16x8 vf = ldb8(sV + c * 32 + chs * 8);
      oacc[0][f] = MFMA16(pf0, vf, oacc[0][f]);
      oacc[1][f] = MFMA16(pf1, vf, oacc[1][f]);
    }
  }
  #pragma unroll
  for (int sub = 0; sub < 2; ++sub)
    #pragma unroll
    for (int r = 0; r < 4; ++r) l4[sub][r] = red_sum16(l4[sub][r]);
  #pragma unroll
  for (int sub = 0; sub < 2; ++sub)
    #pragma unroll
    for (int r = 0; r < 4; ++r) {
      size_t gr = (size_t)kh * 16384 + b * 4096 + i0 + sub * 16 + quad * 4 + r;
      u16* orow = Op + gr * 256;
      #pragma unroll
      for (int f = 0; f < 16; ++f) orow[f * 16 + l16] = f2bf(oacc[sub][f][r]);
      if (l16 == 0) Ol[gr] = l4[sub][r];
    }
}

// ---------- proj + residual, fused 4-quarter merge (identical — verified) ----------
__global__ __launch_bounds__(256) void k_proj(const u16* __restrict__ Op, const float* __restrict__ Ol,
    const u16* __restrict__ Pw, const float* __restrict__ pb, const float* __restrict__ y,
    float* __restrict__ out) {
  __shared__ u16 sA[64 * 136];
  __shared__ u16 sB[64 * 136];
  __shared__ float sW[64];
  int tid = threadIdx.x, w = tid >> 6, lane = tid & 63, quad = lane >> 4, l16 = lane & 15;
  int i0 = blockIdx.x * 64, o0 = blockIdx.y * 64, b = blockIdx.z;
  if (tid < 64) {
    size_t gr = (size_t)b * 4096 + i0 + tid;
    float L = Ol[gr] + Ol[gr + 16384] + Ol[gr + 32768] + Ol[gr + 49152];
    sW[tid] = 1.f / L;
  }
  __syncthreads();
  f32x4 z = {0.f, 0.f, 0.f, 0.f};
  f32x4 acc[4] = {z, z, z, z};
  for (int kc = 0; kc < 2; ++kc) {
    if (kc) __syncthreads();
    #pragma unroll
    for (int p = 0; p < 4; ++p) {
      int q = p * 256 + tid; int row = q >> 4, c8 = q & 15;
      *(uint4*)(sA + row * 136 + c8 * 8) = *(const uint4*)(Pw + ((size_t)(o0 + row)) * 256 + kc * 128 + c8 * 8);
      size_t gr = (size_t)b * 4096 + i0 + row;
      const u16* hp = Op + gr * 256 + kc * 128 + c8 * 8;
      uint4 u0 = *(const uint4*)(hp);
      uint4 u1 = *(const uint4*)(hp + 4194304);
      uint4 u2 = *(const uint4*)(hp + 8388608);
      uint4 u3 = *(const uint4*)(hp + 12582912);
      float wr = sW[row];
      const u16* p0 = (const u16*)&u0; const u16* p1 = (const u16*)&u1;
      const u16* p2 = (const u16*)&u2; const u16* p3 = (const u16*)&u3;
      ushort8 ov;
      #pragma unroll
      for (int e = 0; e < 8; ++e) {
        float v = (b2f(p0[e]) + b2f(p1[e]) + b2f(p2[e]) + b2f(p3[e])) * wr;
        ov[e] = f2bf(v);
      }
      *(ushort8*)(sB + row * 136 + c8 * 8) = ov;
    }
    __syncthreads();
    #pragma unroll
    for (int kk = 0; kk < 4; ++kk) {
      bf16x8 af = ldb8(sA + (w * 16 + l16) * 136 + kk * 32 + quad * 8);
      #pragma unroll
      for (int nb = 0; nb < 4; ++nb) {
        bf16x8 bfr = ldb8(sB + (nb * 16 + l16) * 136 + kk * 32 + quad * 8);
        acc[nb] = MFMA16(af, bfr, acc[nb]);
      }
    }
  }
  #pragma unroll
  for (int nb = 0; nb < 4; ++nb) {
    #pragma unroll
    for (int r = 0; r < 4; ++r) {
      int og = o0 + w * 16 + quad * 4 + r;
      size_t idx = ((size_t)(b * 256 + og)) * 4096 + i0 + nb * 16 + l16;
      out[idx] = y[idx] + acc[nb][r] + pb[og];
    }
  }
}

extern "C" void kernel_launch(void* const* d_in, const int* in_sizes, int n_in,
                              void* d_out, int out_size, void* d_ws, size_t ws_size,
                              hipStream_t stream) {
  (void)in_sizes; (void)n_in; (void)out_size; (void)ws_size;
  const float* x     = (const float*)d_in[0];
  const float* y     = (const float*)d_in[1];
  const float* q_w   = (const float*)d_in[2];
  const float* q_b   = (const float*)d_in[3];
  const float* dw_w  = (const float*)d_in[4];
  const float* dw_b  = (const float*)d_in[5];
  const float* kv_w1 = (const float*)d_in[6];
  const float* kv_b1 = (const float*)d_in[7];
  const float* ln1_g = (const float*)d_in[8];
  const float* ln1_b = (const float*)d_in[9];
  const float* kv_w2 = (const float*)d_in[10];
  const float* kv_b2 = (const float*)d_in[11];
  const float* ln2_g = (const float*)d_in[12];
  const float* ln2_b = (const float*)d_in[13];
  const float* kv_w3 = (const float*)d_in[14];
  const float* kv_b3 = (const float*)d_in[15];
  const float* ln3_g = (const float*)d_in[16];
  const float* ln3_b = (const float*)d_in[17];
  const float* kv_w4 = (const float*)d_in[18];
  const float* kv_b4 = (const float*)d_in[19];
  const float* proj_w = (const float*)d_in[20];
  const float* proj_b = (const float*)d_in[21];
  float* out = (float*)d_out;
  unsigned char* ws = (unsigned char*)d_ws;

  u16* Wt2 = (u16*)(ws + 0);
  u16* Wt3 = (u16*)(ws + 65536);
  u16* Wt4 = (u16*)(ws + 196608);
  u16* Qw  = (u16*)(ws + 458752);
  u16* Pww = (u16*)(ws + 589824);
  u16* Qb  = (u16*)(ws + 9437184);      // 8 MB
  u16* Kt  = (u16*)(ws + 17825792);     // 8 MB
  u16* Vt  = (u16*)(ws + 26214400);     // 8 MB
  u16* Op  = (u16*)(ws + 34603008);     // [4][16384][256] bf16, 32 MB
  float* Ol = (float*)(ws + 68157440);  // [4][16384] f32

  k_prep<<<1408, 256, 0, stream>>>(kv_w2, kv_w3, kv_w4, q_w, proj_w, Wt2, Wt3, Wt4, Qw, Pww);
  k_fused<<<512, 256, 0, stream>>>(x, kv_w1, kv_b1, ln1_g, ln1_b,
                                   Wt2, kv_b2, ln2_g, ln2_b,
                                   Wt3, kv_b3, ln3_g, ln3_b,
                                   Wt4, kv_b4,
                                   y, Qw, q_b, dw_w, dw_b,
                                   Kt, Vt, Qb);
  k_attn<<<512, 256, 0, stream>>>(Qb, Kt, Vt, Op, Ol);
  k_proj<<<dim3(64, 4, 4), 256, 0, stream>>>(Op, Ol, Pww, proj_b, y, out);
}

// Round 9
// 293.764 us; speedup vs baseline: 1.0189x; 1.0189x over previous
//
#include <hip/hip_runtime.h>
#include <cstdint>
#include <cstddef>

using bf16   = __bf16;
using bf16x8 = __bf16 __attribute__((ext_vector_type(8)));
using f32x4  = float  __attribute__((ext_vector_type(4)));
using u16    = unsigned short;
using ushort8 = __attribute__((ext_vector_type(8))) unsigned short;

#define MFMA16(a, b, c) __builtin_amdgcn_mfma_f32_16x16x32_bf16(a, b, c, 0, 0, 0)

__device__ __forceinline__ u16 f2bf(float f) {
  union { float f; unsigned u; } v; v.f = f;
  unsigned r = v.u + 0x7fffu + ((v.u >> 16) & 1u);
  return (u16)(r >> 16);
}
__device__ __forceinline__ u16 bfc(float f) {
  union { float f; unsigned u; } v; v.f = f;
  return (u16)((v.u + 0x8000u) >> 16);
}
__device__ __forceinline__ float b2f(u16 h) {
  union { unsigned u; float f; } v; v.u = ((unsigned)h) << 16; return v.f;
}
__device__ __forceinline__ bf16x8 ldb8(const u16* p) { return *(const bf16x8*)p; }
__device__ __forceinline__ float red_sum16(float v) {
  v += __shfl_xor(v, 1, 64); v += __shfl_xor(v, 2, 64);
  v += __shfl_xor(v, 4, 64); v += __shfl_xor(v, 8, 64);
  return v;
}
__device__ __forceinline__ void gll16(const u16* g, u16* l) {
  __builtin_amdgcn_global_load_lds(
      (const __attribute__((address_space(1))) void*)g,
      (__attribute__((address_space(3))) void*)l, 16, 0, 0);
}

#define QSCALE 0.09016844005556021f  // C^-0.5 * log2(e)

// ---------- prep: weight converts/transposes ----------
__global__ void k_prep(const float* __restrict__ kv_w2, const float* __restrict__ kv_w3,
                       const float* __restrict__ kv_w4, const float* __restrict__ q_w,
                       const float* __restrict__ proj_w,
                       u16* __restrict__ Wt2, u16* __restrict__ Wt3, u16* __restrict__ Wt4,
                       u16* __restrict__ Qw, u16* __restrict__ Pww) {
  int idx = blockIdx.x * 256 + threadIdx.x;
  if (idx < 32768) {                    // kv_w2 [128][256] -> Wt2 [256][128]
    int n = idx >> 7, k = idx & 127;
    Wt2[idx] = f2bf(kv_w2[k * 256 + n]);
  } else if (idx < 98304) {             // kv_w3 [256][256] -> Wt3 [256][256]
    int j = idx - 32768, n = j >> 8, k = j & 255;
    Wt3[j] = f2bf(kv_w3[k * 256 + n]);
  } else if (idx < 229376) {            // kv_w4 [256][512] -> Wt4 [512][256]
    int j = idx - 98304, n = j >> 8, k = j & 255;
    Wt4[j] = f2bf(kv_w4[k * 512 + n]);
  } else if (idx < 294912) {            // q_w already [o][c]
    int j = idx - 229376;
    Qw[j] = f2bf(q_w[j]);
  } else if (idx < 360448) {
    int j = idx - 294912;
    Pww[j] = f2bf(proj_w[j]);
  }
}

// ---------- wave-local MLP layer: B-frags direct from L2, zero barriers ----------
template<int K>
__device__ __forceinline__ void wave_layer(u16* act, const u16* __restrict__ Wt,
    const float* __restrict__ bias, const float* __restrict__ g, const float* __restrict__ bb,
    int quad, int l16) {
  bf16x8 af[K / 32];
  #pragma unroll
  for (int kk = 0; kk < K / 32; ++kk) af[kk] = ldb8(act + l16 * 264 + kk * 32 + quad * 8);
  f32x4 z = {0.f, 0.f, 0.f, 0.f};
  f32x4 acc[16];
  #pragma unroll
  for (int f = 0; f < 16; ++f) acc[f] = z;
  #pragma unroll
  for (int nb = 0; nb < 16; ++nb) {
    const u16* wrow = Wt + (size_t)(nb * 16 + l16) * K + quad * 8;
    #pragma unroll
    for (int kk = 0; kk < K / 32; ++kk)
      acc[nb] = MFMA16(af[kk], ldb8(wrow + kk * 32), acc[nb]);
  }
  #pragma unroll
  for (int f = 0; f < 16; ++f) {
    float bv = bias[f * 16 + l16];
    acc[f][0] += bv; acc[f][1] += bv; acc[f][2] += bv; acc[f][3] += bv;
  }
  #pragma unroll
  for (int r = 0; r < 4; ++r) {
    float s = 0;
    #pragma unroll
    for (int f = 0; f < 16; ++f) s += acc[f][r];
    s = red_sum16(s);
    float mu = s * (1.f / 256.f);
    float vv = 0;
    #pragma unroll
    for (int f = 0; f < 16; ++f) { float d = acc[f][r] - mu; vv += d * d; }
    vv = red_sum16(vv);
    float inv = rsqrtf(vv * (1.f / 256.f) + 1e-5f);
    int rl = quad * 4 + r;
    #pragma unroll
    for (int f = 0; f < 16; ++f) {
      int col = f * 16 + l16;
      float o = (acc[f][r] - mu) * inv * g[col] + bb[col];
      o = o > 0.f ? o : 0.01f * o;
      act[rl * 264 + col] = f2bf(o);
    }
  }
  asm volatile("s_waitcnt lgkmcnt(0)" ::: "memory");
}

// ---------- fused, fully wave-independent: 2048 one-wave blocks, ZERO barriers ----------
// blocks 0..1023: MLP wave (16 rows end-to-end). blocks 1024..2047: Q wave (16 rows).
__global__ __launch_bounds__(64) void k_fused(
    const float* __restrict__ x, const float* __restrict__ w1, const float* __restrict__ bias1,
    const float* __restrict__ g1, const float* __restrict__ bb1,
    const u16* __restrict__ Wt2, const float* __restrict__ bias2,
    const float* __restrict__ g2, const float* __restrict__ bb2,
    const u16* __restrict__ Wt3, const float* __restrict__ bias3,
    const float* __restrict__ g3, const float* __restrict__ bb3,
    const u16* __restrict__ Wt4, const float* __restrict__ bias4,
    const float* __restrict__ y, const u16* __restrict__ Qw,
    const float* __restrict__ qb, const float* __restrict__ dww, const float* __restrict__ dwb,
    u16* __restrict__ Kt, u16* __restrict__ Vt, u16* __restrict__ Qb) {
  __shared__ __align__(16) u16 act[4224];   // [16][264], wave-private (1 wave/block)
  int lane = threadIdx.x, quad = lane >> 4, l16 = lane & 15;
  f32x4 z = {0.f, 0.f, 0.f, 0.f};

  if (blockIdx.x < 1024) {
    // ===== MLP wave: rows rbase..rbase+16 through all 4 layers =====
    int rbase = blockIdx.x * 16;
    {   // layer 1: thread (quad,l16): row l16, cols quad*32..+32
      int c0 = quad * 32;
      float xv = x[rbase + l16];
      float t[32];
      float s = 0.f;
      #pragma unroll
      for (int j = 0; j < 32; ++j) { t[j] = xv * w1[c0 + j] + bias1[c0 + j]; s += t[j]; }
      s += __shfl_xor(s, 16, 64); s += __shfl_xor(s, 32, 64);
      float mu = s * (1.f / 128.f);
      float vv = 0.f;
      #pragma unroll
      for (int j = 0; j < 32; ++j) { float d = t[j] - mu; vv += d * d; }
      vv += __shfl_xor(vv, 16, 64); vv += __shfl_xor(vv, 32, 64);
      float inv = rsqrtf(vv * (1.f / 128.f) + 1e-5f);
      #pragma unroll
      for (int jo = 0; jo < 4; ++jo) {
        ushort8 pk;
        #pragma unroll
        for (int e = 0; e < 8; ++e) {
          int j = jo * 8 + e;
          float o = (t[j] - mu) * inv * g1[c0 + j] + bb1[c0 + j];
          o = o > 0.f ? o : 0.01f * o;
          pk[e] = f2bf(o);
        }
        *(ushort8*)(act + l16 * 264 + c0 + jo * 8) = pk;
      }
    }
    asm volatile("s_waitcnt lgkmcnt(0)" ::: "memory");
    wave_layer<128>(act, Wt2, bias2, g2, bb2, quad, l16);
    wave_layer<256>(act, Wt3, bias3, g3, bb3, quad, l16);
    // ---- layer 4: two N-halves, silu, K/V swizzled tile stores ----
    bf16x8 af[8];
    #pragma unroll
    for (int kk = 0; kk < 8; ++kk) af[kk] = ldb8(act + l16 * 264 + kk * 32 + quad * 8);
    for (int h = 0; h < 2; ++h) {
      f32x4 acc[16];
      #pragma unroll
      for (int f = 0; f < 16; ++f) acc[f] = z;
      #pragma unroll
      for (int nb = 0; nb < 16; ++nb) {
        const u16* wrow = Wt4 + (size_t)(h * 256 + nb * 16 + l16) * 256 + quad * 8;
        #pragma unroll
        for (int kk = 0; kk < 8; ++kk)
          acc[nb] = MFMA16(af[kk], ldb8(wrow + kk * 32), acc[nb]);
      }
      #pragma unroll
      for (int f = 0; f < 16; ++f) {
        int col = f * 16 + l16;
        float bv = bias4[h * 256 + col];
        if (h == 0) {
          int chunk = f * 2 + (l16 >> 3), co = col & 7;
          #pragma unroll
          for (int r = 0; r < 4; ++r) {
            int rowg = rbase + quad * 4 + r;
            float v = acc[f][r] + bv;
            v = v / (1.f + __expf(-v));
            int chs = (chunk + (rowg & 31)) & 31;
            Kt[(size_t)rowg * 256 + chs * 8 + co] = f2bf(v);
          }
        } else {
          int rowg0 = rbase + quad * 4;
          int bb2_ = rowg0 >> 12, d0 = rowg0 & 4095;
          int dd = d0 & 31, qd = dd >> 3;
          int chs = (qd + (col & 3) + ((col >> 2) & 3)) & 3;
          ushort4 u;
          #pragma unroll
          for (int r = 0; r < 4; ++r) {
            float v = acc[f][r] + bv;
            v = v / (1.f + __expf(-v));
            ((u16*)&u)[r] = f2bf(v);
          }
          size_t off = ((size_t)(bb2_ * 128 + (d0 >> 5)) * 8192) + col * 32 + chs * 8 + (dd & 7);
          *(ushort4*)(Vt + off) = u;
        }
      }
    }
    return;
  }

  // ===== Q wave: 16 rows, wave-local transpose + direct-L2 Qw fragments =====
  int grow = (blockIdx.x - 1024) * 16;
  int b = grow >> 12, i0 = grow & 4095;
  // transpose-stage y[b][c][i0..i0+16) -> act[i][c] (fp32 -> bf16)
  #pragma unroll
  for (int p = 0; p < 4; ++p) {
    int c = p * 64 + lane;
    const float* yp = y + ((size_t)(b * 256 + c)) * 4096 + i0;
    #pragma unroll
    for (int g4 = 0; g4 < 4; ++g4) {
      float4 v = *(const float4*)(yp + g4 * 4);
      act[(g4 * 4 + 0) * 264 + c] = f2bf(v.x);
      act[(g4 * 4 + 1) * 264 + c] = f2bf(v.y);
      act[(g4 * 4 + 2) * 264 + c] = f2bf(v.z);
      act[(g4 * 4 + 3) * 264 + c] = f2bf(v.w);
    }
  }
  asm volatile("s_waitcnt lgkmcnt(0)" ::: "memory");
  bf16x8 af[8];
  #pragma unroll
  for (int kk = 0; kk < 8; ++kk) af[kk] = ldb8(act + l16 * 264 + kk * 32 + quad * 8);
  f32x4 acc[16];
  #pragma unroll
  for (int f = 0; f < 16; ++f) acc[f] = z;
  #pragma unroll
  for (int nb = 0; nb < 16; ++nb) {
    const u16* wrow = Qw + (size_t)(nb * 16 + l16) * 256 + quad * 8;
    #pragma unroll
    for (int kk = 0; kk < 8; ++kk)
      acc[nb] = MFMA16(af[kk], ldb8(wrow + kk * 32), acc[nb]);
  }
  #pragma unroll
  for (int f = 0; f < 16; ++f) {
    int col = f * 16 + l16;
    float q0 = qb[col], sc = dww[col], dB = dwb[col];
    #pragma unroll
    for (int r = 0; r < 4; ++r) {
      int rowg = i0 + quad * 4 + r;
      float v = ((acc[f][r] + q0) * sc + dB) * QSCALE;
      Qb[((size_t)(b * 4096 + rowg)) * 256 + col] = f2bf(v);
    }
  }
}

// ---------- flash attention: EXACT round-6 version (verified 91.5 us) ----------
__global__ __launch_bounds__(256, 2) void k_attn(const u16* __restrict__ Qb, const u16* __restrict__ Kt,
    const u16* __restrict__ Vt, u16* __restrict__ Op, float* __restrict__ Ol) {
  __shared__ __align__(16) u16 smem[37888];   // [2][16384] K+V dbuf + [4][1280] P
  int tid = threadIdx.x, w = tid >> 6, lane = tid & 63, quad = lane >> 4, l16 = lane & 15;
  int b = blockIdx.x & 3, kh = (blockIdx.x >> 2) & 3, qt = blockIdx.x >> 4;
  int i0 = qt * 128 + w * 32;

  bf16x8 qf[2][8];
  {
    const u16* qrow = Qb + ((size_t)(b * 4096 + i0 + l16)) * 256 + quad * 8;
    #pragma unroll
    for (int kk = 0; kk < 8; ++kk) {
      qf[0][kk] = ldb8(qrow + kk * 32);
      qf[1][kk] = ldb8(qrow + 16 * 256 + kk * 32);
    }
  }
  f32x4 z = {0.f, 0.f, 0.f, 0.f};
  f32x4 oacc[2][16];
  #pragma unroll
  for (int sub = 0; sub < 2; ++sub)
    #pragma unroll
    for (int f = 0; f < 16; ++f) oacc[sub][f] = z;
  float l4[2][4] = {{0.f, 0.f, 0.f, 0.f}, {0.f, 0.f, 0.f, 0.f}};

  u16* sPw = smem + 32768 + w * 1280;
  int wp = w & 1;
  const u16* gSrc = ((w < 2) ? Kt : Vt) + ((size_t)(b * 128 + kh * 32) * 8192) + wp * 4096 + lane * 8;
  u16* lBase = smem + ((w < 2) ? 0 : 8192) + wp * 4096 + lane * 8;

  #pragma unroll
  for (int i = 0; i < 8; ++i) gll16(gSrc + i * 512, lBase + i * 512);
  gSrc += 8192;

  #pragma unroll 1
  for (int kt = 0; kt < 32; ++kt) {
    int buf = kt & 1;
    const u16* sK = smem + buf * 16384;
    const u16* sV = sK + 8192;
    asm volatile("s_waitcnt vmcnt(0)" ::: "memory");
    __syncthreads();
    if (kt < 31) {
      u16* dst = lBase + (buf ^ 1) * 16384;
      #pragma unroll
      for (int i = 0; i < 8; ++i) gll16(gSrc + i * 512, dst + i * 512);
      gSrc += 8192;
    }
    f32x4 s00 = z, s01 = z, s10 = z, s11 = z;
    #pragma unroll
    for (int kk = 0; kk < 8; ++kk) {
      int ch0 = (kk * 4 + quad + l16) & 31;
      int ch1 = (ch0 + 16) & 31;
      bf16x8 k0 = ldb8(sK + l16 * 256 + ch0 * 8);
      bf16x8 k1 = ldb8(sK + (16 + l16) * 256 + ch1 * 8);
      s00 = MFMA16(qf[0][kk], k0, s00);
      s01 = MFMA16(qf[0][kk], k1, s01);
      s10 = MFMA16(qf[1][kk], k0, s10);
      s11 = MFMA16(qf[1][kk], k1, s11);
    }
    #pragma unroll
    for (int r = 0; r < 4; ++r) {
      float p0 = exp2f(s00[r]);
      float p1 = exp2f(s01[r]);
      float p2 = exp2f(s10[r]);
      float p3 = exp2f(s11[r]);
      l4[0][r] += p0 + p1;
      l4[1][r] += p2 + p3;
      int row0 = (quad * 4 + r) * 40;
      sPw[row0 + l16]            = bfc(p0);
      sPw[row0 + 16 + l16]       = bfc(p1);
      sPw[640 + row0 + l16]      = bfc(p2);
      sPw[640 + row0 + 16 + l16] = bfc(p3);
    }
    asm volatile("s_waitcnt lgkmcnt(0)" ::: "memory");
    bf16x8 pf0 = ldb8(sPw + l16 * 40 + quad * 8);
    bf16x8 pf1 = ldb8(sPw + 640 + l16 * 40 + quad * 8);
    #pragma unroll
    for (int f = 0; f < 16; ++f) {
      int c = f * 16 + l16;
      int chs = (quad + (c & 3) + ((c >> 2) & 3)) & 3;
      bf16x8 vf = ldb8(sV + c * 32 + chs * 8);
      oacc[0][f] = MFMA16(pf0, vf, oacc[0][f]);
      oacc[1][f] = MFMA16(pf1, vf, oacc[1][f]);
    }
  }
  #pragma unroll
  for (int sub = 0; sub < 2; ++sub)
    #pragma unroll
    for (int r = 0; r < 4; ++r) l4[sub][r] = red_sum16(l4[sub][r]);
  #pragma unroll
  for (int sub = 0; sub < 2; ++sub)
    #pragma unroll
    for (int r = 0; r < 4; ++r) {
      size_t gr = (size_t)kh * 16384 + b * 4096 + i0 + sub * 16 + quad * 4 + r;
      u16* orow = Op + gr * 256;
      #pragma unroll
      for (int f = 0; f < 16; ++f) orow[f * 16 + l16] = f2bf(oacc[sub][f][r]);
      if (l16 == 0) Ol[gr] = l4[sub][r];
    }
}

// ---------- proj + residual, fused 4-quarter merge (identical — verified) ----------
__global__ __launch_bounds__(256) void k_proj(const u16* __restrict__ Op, const float* __restrict__ Ol,
    const u16* __restrict__ Pw, const float* __restrict__ pb, const float* __restrict__ y,
    float* __restrict__ out) {
  __shared__ u16 sA[64 * 136];
  __shared__ u16 sB[64 * 136];
  __shared__ float sW[64];
  int tid = threadIdx.x, w = tid >> 6, lane = tid & 63, quad = lane >> 4, l16 = lane & 15;
  int i0 = blockIdx.x * 64, o0 = blockIdx.y * 64, b = blockIdx.z;
  if (tid < 64) {
    size_t gr = (size_t)b * 4096 + i0 + tid;
    float L = Ol[gr] + Ol[gr + 16384] + Ol[gr + 32768] + Ol[gr + 49152];
    sW[tid] = 1.f / L;
  }
  __syncthreads();
  f32x4 z = {0.f, 0.f, 0.f, 0.f};
  f32x4 acc[4] = {z, z, z, z};
  for (int kc = 0; kc < 2; ++kc) {
    if (kc) __syncthreads();
    #pragma unroll
    for (int p = 0; p < 4; ++p) {
      int q = p * 256 + tid; int row = q >> 4, c8 = q & 15;
      *(uint4*)(sA + row * 136 + c8 * 8) = *(const uint4*)(Pw + ((size_t)(o0 + row)) * 256 + kc * 128 + c8 * 8);
      size_t gr = (size_t)b * 4096 + i0 + row;
      const u16* hp = Op + gr * 256 + kc * 128 + c8 * 8;
      uint4 u0 = *(const uint4*)(hp);
      uint4 u1 = *(const uint4*)(hp + 4194304);
      uint4 u2 = *(const uint4*)(hp + 8388608);
      uint4 u3 = *(const uint4*)(hp + 12582912);
      float wr = sW[row];
      const u16* p0 = (const u16*)&u0; const u16* p1 = (const u16*)&u1;
      const u16* p2 = (const u16*)&u2; const u16* p3 = (const u16*)&u3;
      ushort8 ov;
      #pragma unroll
      for (int e = 0; e < 8; ++e) {
        float v = (b2f(p0[e]) + b2f(p1[e]) + b2f(p2[e]) + b2f(p3[e])) * wr;
        ov[e] = f2bf(v);
      }
      *(ushort8*)(sB + row * 136 + c8 * 8) = ov;
    }
    __syncthreads();
    #pragma unroll
    for (int kk = 0; kk < 4; ++kk) {
      bf16x8 af = ldb8(sA + (w * 16 + l16) * 136 + kk * 32 + quad * 8);
      #pragma unroll
      for (int nb = 0; nb < 4; ++nb) {
        bf16x8 bfr = ldb8(sB + (nb * 16 + l16) * 136 + kk * 32 + quad * 8);
        acc[nb] = MFMA16(af, bfr, acc[nb]);
      }
    }
  }
  #pragma unroll
  for (int nb = 0; nb < 4; ++nb) {
    #pragma unroll
    for (int r = 0; r < 4; ++r) {
      int og = o0 + w * 16 + quad * 4 + r;
      size_t idx = ((size_t)(b * 256 + og)) * 4096 + i0 + nb * 16 + l16;
      out[idx] = y[idx] + acc[nb][r] + pb[og];
    }
  }
}

extern "C" void kernel_launch(void* const* d_in, const int* in_sizes, int n_in,
                              void* d_out, int out_size, void* d_ws, size_t ws_size,
                              hipStream_t stream) {
  (void)in_sizes; (void)n_in; (void)out_size; (void)ws_size;
  const float* x     = (const float*)d_in[0];
  const float* y     = (const float*)d_in[1];
  const float* q_w   = (const float*)d_in[2];
  const float* q_b   = (const float*)d_in[3];
  const float* dw_w  = (const float*)d_in[4];
  const float* dw_b  = (const float*)d_in[5];
  const float* kv_w1 = (const float*)d_in[6];
  const float* kv_b1 = (const float*)d_in[7];
  const float* ln1_g = (const float*)d_in[8];
  const float* ln1_b = (const float*)d_in[9];
  const float* kv_w2 = (const float*)d_in[10];
  const float* kv_b2 = (const float*)d_in[11];
  const float* ln2_g = (const float*)d_in[12];
  const float* ln2_b = (const float*)d_in[13];
  const float* kv_w3 = (const float*)d_in[14];
  const float* kv_b3 = (const float*)d_in[15];
  const float* ln3_g = (const float*)d_in[16];
  const float* ln3_b = (const float*)d_in[17];
  const float* kv_w4 = (const float*)d_in[18];
  const float* kv_b4 = (const float*)d_in[19];
  const float* proj_w = (const float*)d_in[20];
  const float* proj_b = (const float*)d_in[21];
  float* out = (float*)d_out;
  unsigned char* ws = (unsigned char*)d_ws;

  u16* Wt2 = (u16*)(ws + 0);
  u16* Wt3 = (u16*)(ws + 65536);
  u16* Wt4 = (u16*)(ws + 196608);
  u16* Qw  = (u16*)(ws + 458752);
  u16* Pww = (u16*)(ws + 589824);
  u16* Qb  = (u16*)(ws + 9437184);      // 8 MB
  u16* Kt  = (u16*)(ws + 17825792);     // 8 MB
  u16* Vt  = (u16*)(ws + 26214400);     // 8 MB
  u16* Op  = (u16*)(ws + 34603008);     // [4][16384][256] bf16, 32 MB
  float* Ol = (float*)(ws + 68157440);  // [4][16384] f32

  k_prep<<<1408, 256, 0, stream>>>(kv_w2, kv_w3, kv_w4, q_w, proj_w, Wt2, Wt3, Wt4, Qw, Pww);
  k_fused<<<2048, 64, 0, stream>>>(x, kv_w1, kv_b1, ln1_g, ln1_b,
                                   Wt2, kv_b2, ln2_g, ln2_b,
                                   Wt3, kv_b3, ln3_g, ln3_b,
                                   Wt4, kv_b4,
                                   y, Qw, q_b, dw_w, dw_b,
                                   Kt, Vt, Qb);
  k_attn<<<512, 256, 0, stream>>>(Qb, Kt, Vt, Op, Ol);
  k_proj<<<dim3(64, 4, 4), 256, 0, stream>>>(Op, Ol, Pww, proj_b, y, out);
}